// Round 3
// baseline (517.264 us; speedup 1.0000x reference)
//
#include <hip/hip_runtime.h>
#include <hip/hip_bf16.h>

#define B_ 8
#define S_ 2048
#define H_ 256
#define BS_ (B_*S_)

typedef __attribute__((ext_vector_type(8))) short bf16x8;
typedef __attribute__((ext_vector_type(4))) short bf16x4;
typedef __attribute__((ext_vector_type(4))) float f32x4;

static __device__ inline short f2bf(float f) {
  union { float f; unsigned int u; } a; a.f = f;
  unsigned int u = a.u;
  unsigned int r = (u + 0x7fffu + ((u >> 16) & 1u)) >> 16;
  return (short)r;
}

static __device__ inline f32x4 mfma16(bf16x8 a, bf16x8 b, f32x4 c) {
  return __builtin_amdgcn_mfma_f32_16x16x32_bf16(a, b, c, 0, 0, 0);
}

// ---------------------------------------------------------------------------
// Kernel 0: fp32 -> bf16 conversion of x, Wq, Wk, Wv into workspace.
// ---------------------------------------------------------------------------
#define NX4 (BS_ * H_ / 4)
#define NW4 (H_ * H_ / 4)
#define NTOT4 (NX4 + 3 * NW4)

__global__ __launch_bounds__(256) void cvt_bf16(
    const float* __restrict__ x,
    const float* __restrict__ Wq, const float* __restrict__ Wk,
    const float* __restrict__ Wv,
    short* __restrict__ xb, short* __restrict__ wqb,
    short* __restrict__ wkb, short* __restrict__ wvb)
{
  int stride = gridDim.x * blockDim.x;
  for (int i = blockIdx.x * blockDim.x + threadIdx.x; i < NTOT4; i += stride) {
    const float* src; short* dst; int off;
    if (i < NX4) { src = x; dst = xb; off = i; }
    else {
      int j = i - NX4;
      int w = j >> 14;
      off = j & (NW4 - 1);
      src = (w == 0) ? Wq : (w == 1) ? Wk : Wv;
      dst = (w == 0) ? wqb : (w == 1) ? wkb : wvb;
    }
    float4 v = *(const float4*)(src + off * 4);
    bf16x4 p;
    p[0] = f2bf(v.x); p[1] = f2bf(v.y); p[2] = f2bf(v.z); p[3] = f2bf(v.w);
    *(bf16x4*)(dst + off * 4) = p;
  }
}

// ---------------------------------------------------------------------------
// Kernel 1: Q/K row-major + V transposed. grid (BS/64, 3), block 256.
// ---------------------------------------------------------------------------
__global__ __launch_bounds__(256) void qkv_proj(
    const short* __restrict__ x,
    const short* __restrict__ Wq, const float* __restrict__ bq,
    const short* __restrict__ Wk, const float* __restrict__ bk,
    const short* __restrict__ Wv, const float* __restrict__ bv,
    short* __restrict__ Qo, short* __restrict__ Ko, short* __restrict__ VTo)
{
  const int tid  = threadIdx.x;
  const int wave = tid >> 6;
  const int lane = tid & 63;
  const int quad = lane >> 4;
  const int l16  = lane & 15;
  const int y    = blockIdx.y;

  const short* W    = (y == 0) ? Wq : (y == 1) ? Wk : Wv;
  const float* bias = (y == 0) ? bq : (y == 1) ? bk : bv;
  const int s0 = blockIdx.x * 64 + wave * 16;

  f32x4 zero = {0.f, 0.f, 0.f, 0.f};
  f32x4 acc[16];
#pragma unroll
  for (int i = 0; i < 16; i++) acc[i] = zero;

  const short* xrow = x + (s0 + l16) * H_ + quad * 8;
#pragma unroll
  for (int ks = 0; ks < 8; ks++) {
    bf16x8 a = *(const bf16x8*)(xrow + ks * 32);
#pragma unroll
    for (int nf = 0; nf < 16; nf++) {
      bf16x8 bb = *(const bf16x8*)(W + (nf * 16 + l16) * H_ + ks * 32 + quad * 8);
      acc[nf] = mfma16(a, bb, acc[nf]);
    }
  }

  if (y < 2) {
    short* dst = (y == 0) ? Qo : Ko;
#pragma unroll
    for (int nf = 0; nf < 16; nf++) {
      int col = nf * 16 + l16;
      float bvl = bias[col];
#pragma unroll
      for (int r = 0; r < 4; r++) {
        int row = s0 + quad * 4 + r;
        dst[row * H_ + col] = f2bf(acc[nf][r] + bvl);
      }
    }
  } else {
    int row0  = s0 + quad * 4;
    int b_idx = row0 >> 11;
    int k0    = row0 & (S_ - 1);
#pragma unroll
    for (int nf = 0; nf < 16; nf++) {
      int col = nf * 16 + l16;
      float bvl = bias[col];
      bf16x4 pk;
#pragma unroll
      for (int r = 0; r < 4; r++) pk[r] = f2bf(acc[nf][r] + bvl);
      *(bf16x4*)(VTo + (size_t)b_idx * H_ * S_ + (size_t)col * S_ + k0) = pk;
    }
  }
}

// ---------------------------------------------------------------------------
// Kernel 2a: partial column denominators over a q-slice of 512.
// grid (256, 4): x=(b,kblk), y=qslice. dpart[qs][b*S+k] = sum over slice.
// ---------------------------------------------------------------------------
__global__ __launch_bounds__(256) void col_denom_part(
    const short* __restrict__ Q, const short* __restrict__ K,
    float* __restrict__ dpart)
{
  const int tid  = threadIdx.x;
  const int wave = tid >> 6;
  const int lane = tid & 63;
  const int quad = lane >> 4;
  const int l16  = lane & 15;
  const int b    = blockIdx.x >> 5;
  const int kblk = blockIdx.x & 31;
  const int qs   = blockIdx.y;
  const int colbase = kblk * 64;

  const short* Qb = Q + b * S_ * H_;
  const short* Kb = K + b * S_ * H_;

  f32x4 zero = {0.f, 0.f, 0.f, 0.f};
  float csum[4] = {0.f, 0.f, 0.f, 0.f};

  for (int q0 = qs * 512; q0 < qs * 512 + 512; q0 += 64) {
    f32x4 sacc[4];
#pragma unroll
    for (int nf = 0; nf < 4; nf++) sacc[nf] = zero;
    const short* qrow = Qb + (q0 + wave * 16 + l16) * H_ + quad * 8;
#pragma unroll
    for (int ks = 0; ks < 8; ks++) {
      bf16x8 a = *(const bf16x8*)(qrow + ks * 32);
#pragma unroll
      for (int nf = 0; nf < 4; nf++) {
        bf16x8 bb = *(const bf16x8*)(Kb + (colbase + nf * 16 + l16) * H_ + ks * 32 + quad * 8);
        sacc[nf] = mfma16(a, bb, sacc[nf]);
      }
    }
#pragma unroll
    for (int nf = 0; nf < 4; nf++) {
#pragma unroll
      for (int r = 0; r < 4; r++)
        csum[nf] += __expf(sacc[nf][r] * (1.0f / H_));
    }
  }

#pragma unroll
  for (int nf = 0; nf < 4; nf++) {
    csum[nf] += __shfl_xor(csum[nf], 16, 64);
    csum[nf] += __shfl_xor(csum[nf], 32, 64);
  }

  __shared__ float red[4][64];
  if (lane < 16) {
#pragma unroll
    for (int nf = 0; nf < 4; nf++) red[wave][nf * 16 + lane] = csum[nf];
  }
  __syncthreads();
  if (tid < 64) {
    float s = red[0][tid] + red[1][tid] + red[2][tid] + red[3][tid];
    dpart[qs * BS_ + b * S_ + colbase + tid] = s;
  }
}

// ---------------------------------------------------------------------------
// Kernel 2b: rcp_den = 1 / sum of 4 partials. BS_=16384 elems.
// ---------------------------------------------------------------------------
__global__ __launch_bounds__(256) void den_reduce(
    const float* __restrict__ dpart, float* __restrict__ rcp_den)
{
  int i = blockIdx.x * 256 + threadIdx.x;
  if (i < BS_) {
    float s = dpart[i] + dpart[BS_ + i] + dpart[2 * BS_ + i] + dpart[3 * BS_ + i];
    rcp_den[i] = 1.0f / s;
  }
}

// ---------------------------------------------------------------------------
// Kernel 3: out[b][q][h0+*] for an h-slice of 128.
// grid (256, 2): x=(b,qblk), y=h-slice. block 256 (4 waves x 16 q-rows).
// No __syncthreads: each wave round-trips its private pbuf region; DS ops
// from one wave execute in program order (wave_barrier pins compiler order).
// ---------------------------------------------------------------------------
__global__ __launch_bounds__(256) void attn_out(
    const short* __restrict__ Q, const short* __restrict__ K,
    const short* __restrict__ VT, const float* __restrict__ rcp_den,
    float* __restrict__ out)
{
  const int tid  = threadIdx.x;
  const int wave = tid >> 6;
  const int lane = tid & 63;
  const int quad = lane >> 4;
  const int l16  = lane & 15;
  const int b    = blockIdx.x >> 5;
  const int qblk = blockIdx.x & 31;
  const int h0   = blockIdx.y * 128;

  const short* Qb  = Q + b * S_ * H_;
  const short* Kb  = K + b * S_ * H_;
  const short* VTb = VT + (size_t)b * H_ * S_ + (size_t)h0 * S_;
  const float* rd  = rcp_den + b * S_;
  const int rowq   = qblk * 64 + wave * 16;

  __shared__ short pbuf[4][16 * 72];
  short* pw = &pbuf[wave][0];

  bf16x8 afr[8];
#pragma unroll
  for (int ks = 0; ks < 8; ks++)
    afr[ks] = *(const bf16x8*)(Qb + (rowq + l16) * H_ + ks * 32 + quad * 8);

  f32x4 zero = {0.f, 0.f, 0.f, 0.f};
  f32x4 oacc[8];
#pragma unroll
  for (int i = 0; i < 8; i++) oacc[i] = zero;

  for (int kc = 0; kc < S_; kc += 64) {
    f32x4 sacc[4];
#pragma unroll
    for (int nf = 0; nf < 4; nf++) sacc[nf] = zero;
#pragma unroll
    for (int ks = 0; ks < 8; ks++) {
#pragma unroll
      for (int nf = 0; nf < 4; nf++) {
        bf16x8 bb = *(const bf16x8*)(Kb + (kc + nf * 16 + l16) * H_ + ks * 32 + quad * 8);
        sacc[nf] = mfma16(afr[ks], bb, sacc[nf]);
      }
    }
#pragma unroll
    for (int nf = 0; nf < 4; nf++) {
      float r_d = rd[kc + nf * 16 + l16];
      int col = nf * 16 + l16;
#pragma unroll
      for (int r = 0; r < 4; r++) {
        float p = __expf(sacc[nf][r] * (1.0f / H_)) * r_d;
        pw[(quad * 4 + r) * 72 + col] = f2bf(p);
      }
    }
    __builtin_amdgcn_wave_barrier();   // compiler fence: keep writes before reads
#pragma unroll
    for (int st = 0; st < 2; st++) {
      bf16x8 pa = *(const bf16x8*)(pw + l16 * 72 + st * 32 + quad * 8);
#pragma unroll
      for (int nf2 = 0; nf2 < 8; nf2++) {
        bf16x8 vb = *(const bf16x8*)(VTb + (size_t)(nf2 * 16 + l16) * S_ + kc + st * 32 + quad * 8);
        oacc[nf2] = mfma16(pa, vb, oacc[nf2]);
      }
    }
    __builtin_amdgcn_wave_barrier();   // keep next iter's writes after reads
  }

#pragma unroll
  for (int nf2 = 0; nf2 < 8; nf2++) {
    int col = h0 + nf2 * 16 + l16;
#pragma unroll
    for (int r = 0; r < 4; r++) {
      int q = rowq + quad * 4 + r;
      out[((size_t)b * S_ + q) * H_ + col] = oacc[nf2][r];
    }
  }
}

extern "C" void kernel_launch(void* const* d_in, const int* in_sizes, int n_in,
                              void* d_out, int out_size, void* d_ws, size_t ws_size,
                              hipStream_t stream) {
  const float* x  = (const float*)d_in[0];
  const float* Wq = (const float*)d_in[1];
  const float* bq = (const float*)d_in[2];
  const float* Wk = (const float*)d_in[3];
  const float* bk = (const float*)d_in[4];
  const float* Wv = (const float*)d_in[5];
  const float* bv = (const float*)d_in[6];

  short* xb  = (short*)d_ws;                    // 8 MiB
  short* wqb = xb  + (size_t)BS_ * H_;          // 128 KiB each
  short* wkb = wqb + H_ * H_;
  short* wvb = wkb + H_ * H_;
  short* Qs  = wvb + H_ * H_;                   // 8 MiB
  short* Ks  = Qs  + (size_t)BS_ * H_;          // 8 MiB
  short* VT  = Ks  + (size_t)BS_ * H_;          // 8 MiB
  float* dpart = (float*)(VT + (size_t)BS_ * H_);   // 4*64 KiB
  float* rd  = dpart + 4 * BS_;                 // 64 KiB
  float* outp = (float*)d_out;

  cvt_bf16<<<1024, 256, 0, stream>>>(x, Wq, Wk, Wv, xb, wqb, wkb, wvb);
  qkv_proj<<<dim3(BS_ / 64, 3), 256, 0, stream>>>(xb, wqb, bq, wkb, bk, wvb, bv, Qs, Ks, VT);
  col_denom_part<<<dim3(256, 4), 256, 0, stream>>>(Qs, Ks, dpart);
  den_reduce<<<64, 256, 0, stream>>>(dpart, rd);
  attn_out<<<dim3(256, 2), 256, 0, stream>>>(Qs, Ks, VT, rd, outp);
}

// Round 4
// 354.113 us; speedup vs baseline: 1.4607x; 1.4607x over previous
//
#include <hip/hip_runtime.h>
#include <hip/hip_bf16.h>

#define B_ 8
#define S_ 2048
#define H_ 256
#define BS_ (B_*S_)

typedef __attribute__((ext_vector_type(8))) short bf16x8;
typedef __attribute__((ext_vector_type(4))) short bf16x4;
typedef __attribute__((ext_vector_type(4))) float f32x4;

static __device__ inline short f2bf(float f) {
  union { float f; unsigned int u; } a; a.f = f;
  unsigned int u = a.u;
  unsigned int r = (u + 0x7fffu + ((u >> 16) & 1u)) >> 16;
  return (short)r;
}

static __device__ inline float bf2f(short s) {
  union { float f; unsigned int u; } a;
  a.u = ((unsigned int)(unsigned short)s) << 16;
  return a.f;
}

static __device__ inline f32x4 mfma16(bf16x8 a, bf16x8 b, f32x4 c) {
  return __builtin_amdgcn_mfma_f32_16x16x32_bf16(a, b, c, 0, 0, 0);
}

// ---------------------------------------------------------------------------
// Kernel 0: fp32 -> bf16 conversion of x, Wq, Wk, Wv into workspace.
// ---------------------------------------------------------------------------
#define NX4 (BS_ * H_ / 4)
#define NW4 (H_ * H_ / 4)
#define NTOT4 (NX4 + 3 * NW4)

__global__ __launch_bounds__(256) void cvt_bf16(
    const float* __restrict__ x,
    const float* __restrict__ Wq, const float* __restrict__ Wk,
    const float* __restrict__ Wv,
    short* __restrict__ xb, short* __restrict__ wqb,
    short* __restrict__ wkb, short* __restrict__ wvb)
{
  int stride = gridDim.x * blockDim.x;
  for (int i = blockIdx.x * blockDim.x + threadIdx.x; i < NTOT4; i += stride) {
    const float* src; short* dst; int off;
    if (i < NX4) { src = x; dst = xb; off = i; }
    else {
      int j = i - NX4;
      int w = j >> 14;
      off = j & (NW4 - 1);
      src = (w == 0) ? Wq : (w == 1) ? Wk : Wv;
      dst = (w == 0) ? wqb : (w == 1) ? wkb : wvb;
    }
    float4 v = *(const float4*)(src + off * 4);
    bf16x4 p;
    p[0] = f2bf(v.x); p[1] = f2bf(v.y); p[2] = f2bf(v.z); p[3] = f2bf(v.w);
    *(bf16x4*)(dst + off * 4) = p;
  }
}

// ---------------------------------------------------------------------------
// Kernel 1: Q/K row-major + V transposed [b][h][k]. grid (BS/64, 3), block 256.
// ---------------------------------------------------------------------------
__global__ __launch_bounds__(256) void qkv_proj(
    const short* __restrict__ x,
    const short* __restrict__ Wq, const float* __restrict__ bq,
    const short* __restrict__ Wk, const float* __restrict__ bk,
    const short* __restrict__ Wv, const float* __restrict__ bv,
    short* __restrict__ Qo, short* __restrict__ Ko, short* __restrict__ VTo)
{
  const int tid  = threadIdx.x;
  const int wave = tid >> 6;
  const int lane = tid & 63;
  const int quad = lane >> 4;
  const int l16  = lane & 15;
  const int y    = blockIdx.y;

  const short* W    = (y == 0) ? Wq : (y == 1) ? Wk : Wv;
  const float* bias = (y == 0) ? bq : (y == 1) ? bk : bv;
  const int s0 = blockIdx.x * 64 + wave * 16;

  f32x4 zero = {0.f, 0.f, 0.f, 0.f};
  f32x4 acc[16];
#pragma unroll
  for (int i = 0; i < 16; i++) acc[i] = zero;

  const short* xrow = x + (s0 + l16) * H_ + quad * 8;
#pragma unroll
  for (int ks = 0; ks < 8; ks++) {
    bf16x8 a = *(const bf16x8*)(xrow + ks * 32);
#pragma unroll
    for (int nf = 0; nf < 16; nf++) {
      bf16x8 bb = *(const bf16x8*)(W + (nf * 16 + l16) * H_ + ks * 32 + quad * 8);
      acc[nf] = mfma16(a, bb, acc[nf]);
    }
  }

  if (y < 2) {
    short* dst = (y == 0) ? Qo : Ko;
#pragma unroll
    for (int nf = 0; nf < 16; nf++) {
      int col = nf * 16 + l16;
      float bvl = bias[col];
#pragma unroll
      for (int r = 0; r < 4; r++) {
        int row = s0 + quad * 4 + r;
        dst[row * H_ + col] = f2bf(acc[nf][r] + bvl);
      }
    }
  } else {
    int row0  = s0 + quad * 4;
    int b_idx = row0 >> 11;
    int k0    = row0 & (S_ - 1);
#pragma unroll
    for (int nf = 0; nf < 16; nf++) {
      int col = nf * 16 + l16;
      float bvl = bias[col];
      bf16x4 pk;
#pragma unroll
      for (int r = 0; r < 4; r++) pk[r] = f2bf(acc[nf][r] + bvl);
      *(bf16x4*)(VTo + (size_t)b_idx * H_ * S_ + (size_t)col * S_ + k0) = pk;
    }
  }
}

// ---------------------------------------------------------------------------
// Kernel 2a: zero the denominator accumulator (ws is poisoned 0xAA).
// ---------------------------------------------------------------------------
__global__ __launch_bounds__(256) void zero_den(float* __restrict__ den)
{
  int i = blockIdx.x * 256 + threadIdx.x;
  if (i < BS_) den[i] = 0.f;
}

// ---------------------------------------------------------------------------
// Kernel 2b: P = exp(QK^T/256) stored row-major [b][q][k], computed as the
// TRANSPOSED tile S^T = K.Q^T so C-frag regs are 4 contiguous k -> bf16x4
// coalesced stores. den[b][k] += row-sums (16-lane butterfly + atomicAdd).
// grid 2048 = b(8) x kt(16) x qt(16), block 256 (wave owns 32 k-rows).
// ---------------------------------------------------------------------------
__global__ __launch_bounds__(256) void scores(
    const short* __restrict__ Q, const short* __restrict__ K,
    short* __restrict__ P, float* __restrict__ den)
{
  const int tid  = threadIdx.x;
  const int wave = tid >> 6;
  const int lane = tid & 63;
  const int quad = lane >> 4;
  const int l16  = lane & 15;
  const int qt = blockIdx.x & 15;
  const int kt = (blockIdx.x >> 4) & 15;
  const int b  = blockIdx.x >> 8;

  const short* Qb = Q + b * S_ * H_;
  const short* Kb = K + b * S_ * H_;
  short* Pb = P + (size_t)b * S_ * S_;

  const int krow0 = kt * 128 + wave * 32;
  const int qcol0 = qt * 128;

  f32x4 zero = {0.f, 0.f, 0.f, 0.f};
  f32x4 acc[2][8];
#pragma unroll
  for (int i = 0; i < 2; i++)
#pragma unroll
    for (int j = 0; j < 8; j++) acc[i][j] = zero;

#pragma unroll
  for (int kk = 0; kk < 8; kk++) {
    bf16x8 a0 = *(const bf16x8*)(Kb + (krow0 + l16) * H_ + kk * 32 + quad * 8);
    bf16x8 a1 = *(const bf16x8*)(Kb + (krow0 + 16 + l16) * H_ + kk * 32 + quad * 8);
#pragma unroll
    for (int qf = 0; qf < 8; qf++) {
      bf16x8 bq = *(const bf16x8*)(Qb + (qcol0 + qf * 16 + l16) * H_ + kk * 32 + quad * 8);
      acc[0][qf] = mfma16(a0, bq, acc[0][qf]);
      acc[1][qf] = mfma16(a1, bq, acc[1][qf]);
    }
  }

  float rs[2][4] = {{0.f,0.f,0.f,0.f},{0.f,0.f,0.f,0.f}};
#pragma unroll
  for (int kf = 0; kf < 2; kf++) {
#pragma unroll
    for (int qf = 0; qf < 8; qf++) {
      bf16x4 pk;
#pragma unroll
      for (int r = 0; r < 4; r++) {
        float e = __expf(acc[kf][qf][r] * (1.0f / H_));
        rs[kf][r] += e;
        pk[r] = f2bf(e);
      }
      int q = qcol0 + qf * 16 + l16;
      int k = krow0 + kf * 16 + quad * 4;
      *(bf16x4*)(Pb + (size_t)q * S_ + k) = pk;
    }
  }

  // row-sum = denominator partial for k = krow0 + kf*16 + quad*4 + r
#pragma unroll
  for (int kf = 0; kf < 2; kf++) {
#pragma unroll
    for (int r = 0; r < 4; r++) {
      float v = rs[kf][r];
      v += __shfl_xor(v, 1, 64);
      v += __shfl_xor(v, 2, 64);
      v += __shfl_xor(v, 4, 64);
      v += __shfl_xor(v, 8, 64);
      if (l16 == 0)
        atomicAdd(&den[b * S_ + krow0 + kf * 16 + quad * 4 + r], v);
    }
  }
}

// ---------------------------------------------------------------------------
// Kernel 2c: rcp = 1/den.
// ---------------------------------------------------------------------------
__global__ __launch_bounds__(256) void den_rcp(
    const float* __restrict__ den, float* __restrict__ rcp)
{
  int i = blockIdx.x * 256 + threadIdx.x;
  if (i < BS_) rcp[i] = 1.0f / den[i];
}

// ---------------------------------------------------------------------------
// Kernel 2d: VT[b][h][k] *= rcp[b][k]  (fold softmax denom into V).
// ---------------------------------------------------------------------------
__global__ __launch_bounds__(256) void vscale(
    short* __restrict__ VT, const float* __restrict__ rcp)
{
  int i = blockIdx.x * 256 + threadIdx.x;     // bf16x4 group, k fastest
  int b  = i >> 17;                           // H*S/4 = 131072 groups/batch
  int k0 = (i & 511) << 2;                    // S/4 = 512 groups per h-row
  float4 rf = *(const float4*)(rcp + b * S_ + k0);
  bf16x4 v = *(bf16x4*)(VT + (size_t)i * 4);
  bf16x4 o;
  o[0] = f2bf(bf2f(v[0]) * rf.x);
  o[1] = f2bf(bf2f(v[1]) * rf.y);
  o[2] = f2bf(bf2f(v[2]) * rf.z);
  o[3] = f2bf(bf2f(v[3]) * rf.w);
  *(bf16x4*)(VT + (size_t)i * 4) = o;
}

// ---------------------------------------------------------------------------
// Kernel 3: out = P . Vs  (A = P row-major, B = VT k-contiguous).
// grid 512 = b(8) x qt(32) x hs(2), block 256; wave owns 16 q x 128 h.
// ---------------------------------------------------------------------------
__global__ __launch_bounds__(256) void pv(
    const short* __restrict__ P, const short* __restrict__ VTs,
    float* __restrict__ out)
{
  const int tid  = threadIdx.x;
  const int wave = tid >> 6;
  const int lane = tid & 63;
  const int quad = lane >> 4;
  const int l16  = lane & 15;
  const int b  = blockIdx.x >> 6;
  const int qt = (blockIdx.x >> 1) & 31;
  const int hs = blockIdx.x & 1;

  const short* Pb = P + (size_t)b * S_ * S_;
  const short* Vb = VTs + (size_t)b * H_ * S_ + (size_t)(hs * 128) * S_;
  const int q0 = qt * 64 + wave * 16;

  f32x4 zero = {0.f, 0.f, 0.f, 0.f};
  f32x4 acc[8];
#pragma unroll
  for (int i = 0; i < 8; i++) acc[i] = zero;

  const short* prow = Pb + (size_t)(q0 + l16) * S_ + quad * 8;
#pragma unroll 2
  for (int kk = 0; kk < 64; kk++) {
    bf16x8 a = *(const bf16x8*)(prow + kk * 32);
#pragma unroll
    for (int n = 0; n < 8; n++) {
      bf16x8 vb = *(const bf16x8*)(Vb + (size_t)(n * 16 + l16) * S_ + kk * 32 + quad * 8);
      acc[n] = mfma16(a, vb, acc[n]);
    }
  }

#pragma unroll
  for (int n = 0; n < 8; n++) {
    int col = hs * 128 + n * 16 + l16;
#pragma unroll
    for (int r = 0; r < 4; r++) {
      int q = q0 + quad * 4 + r;
      out[((size_t)b * S_ + q) * H_ + col] = acc[n][r];
    }
  }
}

extern "C" void kernel_launch(void* const* d_in, const int* in_sizes, int n_in,
                              void* d_out, int out_size, void* d_ws, size_t ws_size,
                              hipStream_t stream) {
  const float* x  = (const float*)d_in[0];
  const float* Wq = (const float*)d_in[1];
  const float* bq = (const float*)d_in[2];
  const float* Wk = (const float*)d_in[3];
  const float* bk = (const float*)d_in[4];
  const float* Wv = (const float*)d_in[5];
  const float* bv = (const float*)d_in[6];

  short* xb  = (short*)d_ws;                       // 8 MiB
  short* wqb = xb  + (size_t)BS_ * H_;             // 128 KiB each
  short* wkb = wqb + H_ * H_;
  short* wvb = wkb + H_ * H_;
  short* Qs  = wvb + H_ * H_;                      // 8 MiB
  short* Ks  = Qs  + (size_t)BS_ * H_;             // 8 MiB
  short* VT  = Ks  + (size_t)BS_ * H_;             // 8 MiB
  short* P   = VT  + (size_t)BS_ * H_;             // 64 MiB
  float* den = (float*)(P + (size_t)B_ * S_ * S_); // 64 KiB
  float* rcp = den + BS_;                          // 64 KiB
  float* outp = (float*)d_out;

  cvt_bf16<<<1024, 256, 0, stream>>>(x, Wq, Wk, Wv, xb, wqb, wkb, wvb);
  qkv_proj<<<dim3(BS_ / 64, 3), 256, 0, stream>>>(xb, wqb, bq, wkb, bk, wvb, bv, Qs, Ks, VT);
  zero_den<<<64, 256, 0, stream>>>(den);
  scores<<<2048, 256, 0, stream>>>(Qs, Ks, P, den);
  den_rcp<<<64, 256, 0, stream>>>(den, rcp);
  vscale<<<4096, 256, 0, stream>>>(VT, rcp);
  pv<<<512, 256, 0, stream>>>(P, VT, outp);
}